// Round 1
// 831.280 us; speedup vs baseline: 1.0824x; 1.0824x over previous
//
#include <hip/hip_runtime.h>
#include <hip/hip_bf16.h>
#include <math.h>

// DLRM forward, bf16-MFMA version, round 1 polish.
// - convert+bot0 fused into one launch
// - GEMMs: 128x64 tiles (2-4 blocks/CU vs 1) + bijective XCD swizzle
// - interact: register-staged fully-unrolled gather, Gram via 16x16x32 bf16 MFMA,
//   h-row assembled in LDS and stored coalesced

#define BATCH 16384
#define NTAB 26
#define VOCAB 100000
#define MSPA 64
#define NPAIR 351
#define HPAD 416          // 64 + 351 = 415, padded to 416 (K % 32 == 0)

typedef __bf16 bf16x8 __attribute__((ext_vector_type(8)));
typedef __bf16 bf16x4 __attribute__((ext_vector_type(4)));
typedef float  f32x4  __attribute__((ext_vector_type(4)));

__device__ __forceinline__ void gload_lds16(const __hip_bfloat16* g, void* lds) {
    __builtin_amdgcn_global_load_lds(
        (const __attribute__((address_space(1))) unsigned int*)g,
        (__attribute__((address_space(3))) unsigned int*)lds, 16, 0, 0);
}

// bijective XCD swizzle (all our grids have nwg % 8 == 0): consecutive logical
// tiles (same A-panel) land on the same XCD's L2.
__device__ __forceinline__ void xcd_tile(int& bx, int& by) {
    const int gdx = gridDim.x;
    const int nwg = gdx * gridDim.y;
    const int fid = blockIdx.y * gdx + blockIdx.x;
    const int swz = (fid & 7) * (nwg >> 3) + (fid >> 3);
    bx = swz % gdx;
    by = swz / gdx;
}

// ---------------- bf16 MFMA GEMM: C = relu(A @ Wt^T + bias) ----------------
// A [M,K] bf16 row-major, Wt [N,K] bf16 row-major, C [M,N] OutT.
// 128x64 tile, 256 threads / 4 waves, each wave a 64x32 quadrant (acc 4x2).
template <typename OutT>
__global__ __launch_bounds__(256) void mfma_gemm64(
    const __hip_bfloat16* __restrict__ A, const __hip_bfloat16* __restrict__ Wt,
    const float* __restrict__ bias, OutT* __restrict__ C,
    int M, int N, int K)
{
    __shared__ __hip_bfloat16 As[128 * 32];   // [m][k], k contiguous
    __shared__ __hip_bfloat16 Bs[64 * 32];    // [n][k], k contiguous

    int bx, by;
    xcd_tile(bx, by);
    const int tid  = threadIdx.x;
    const int wave = tid >> 6;
    const int lane = tid & 63;
    const int m0 = by * 128;
    const int n0 = bx * 64;
    const int wm = (wave & 1) * 64;     // wave quadrant within 128x64
    const int wn = (wave >> 1) * 32;

    f32x4 acc[4][2] = {};

    // staging: wave w covers A rows [w*32, w*32+32) (2 gloads), B rows [w*16, w*16+16)
    const int srow = wave * 32 + (lane >> 2);
    const int brow = wave * 16 + (lane >> 2);
    const int scol = (lane & 3) * 8;
    const __hip_bfloat16* ga = A  + (size_t)(m0 + srow) * K + scol;
    const __hip_bfloat16* gb = Wt + (size_t)(n0 + brow) * K + scol;
    char* as_base = (char*)As + (size_t)(wave * 32) * 64;   // row stride 64 B
    char* bs_base = (char*)Bs + (size_t)(wave * 16) * 64;

    // fragment read pointers (verified 16x16x32 layout: row=lane&15, k=(lane>>4)*8)
    const __hip_bfloat16* ar = As + (size_t)(wm + (lane & 15)) * 32 + (lane >> 4) * 8;
    const __hip_bfloat16* br = Bs + (size_t)(wn + (lane & 15)) * 32 + (lane >> 4) * 8;

    for (int k0 = 0; k0 < K; k0 += 32) {
        gload_lds16(ga + k0,           as_base);
        gload_lds16(ga + 16 * K + k0,  as_base + 1024);
        gload_lds16(gb + k0,           bs_base);
        __syncthreads();

        bf16x8 af[4], bfr[2];
        #pragma unroll
        for (int i = 0; i < 4; ++i) af[i] = *(const bf16x8*)(ar + i * 16 * 32);
        #pragma unroll
        for (int j = 0; j < 2; ++j) bfr[j] = *(const bf16x8*)(br + j * 16 * 32);
        #pragma unroll
        for (int i = 0; i < 4; ++i)
            #pragma unroll
            for (int j = 0; j < 2; ++j)
                acc[i][j] = __builtin_amdgcn_mfma_f32_16x16x32_bf16(af[i], bfr[j], acc[i][j], 0, 0, 0);
        __syncthreads();
    }

    // epilogue: C/D layout col=lane&15, row=(lane>>4)*4+reg
    #pragma unroll
    for (int j = 0; j < 2; ++j) {
        const int col = n0 + wn + j * 16 + (lane & 15);
        const float bv = bias[col];
        #pragma unroll
        for (int i = 0; i < 4; ++i) {
            const int row = m0 + wm + i * 16 + (lane >> 4) * 4;
            #pragma unroll
            for (int r = 0; r < 4; ++r) {
                float v = acc[i][j][r] + bv;
                v = v > 0.f ? v : 0.f;
                if constexpr (sizeof(OutT) == 2)
                    C[(size_t)(row + r) * N + col] = (OutT)__float2bfloat16(v);
                else
                    C[(size_t)(row + r) * N + col] = (OutT)v;
            }
        }
    }
}

// ---------------- weight convert/transpose (fp32 [K,N] -> bf16 [Npad,Kpad]) ----
__device__ __forceinline__ void cvt_one(int i, const float* src, __hip_bfloat16* dst,
                                        int K, int N, int Kpad) {
    int n = i / Kpad, k = i - n * Kpad;
    float v = (k < K && n < N) ? src[(size_t)k * N + n] : 0.f;
    dst[i] = __float2bfloat16(v);
}

#define CVT0 131072   // Wb1t 256x512
#define CVT1 32768    // Wb2t 128x256
#define CVT2 212992   // Wt0t 512x416
#define CVT3 131072   // Wt1t 256x512
#define CVT_TOTAL (CVT0 + CVT1 + CVT2 + CVT3 + 128)
#define CVT_BLOCKS ((CVT_TOTAL + 255) / 256)

// ---------------- fused: weight convert + bottom layer 0 ----------------
__global__ __launch_bounds__(256) void fused_cvt_bot0(
    const float* __restrict__ Wb1, const float* __restrict__ Wb2,
    const float* __restrict__ Wt0, const float* __restrict__ Wt1,
    const float* __restrict__ bb2,
    __hip_bfloat16* Wb1t, __hip_bfloat16* Wb2t,
    __hip_bfloat16* Wt0t, __hip_bfloat16* Wt1t, float* bb2p,
    const float* __restrict__ dense, const float* __restrict__ Wb0,
    const float* __restrict__ bb0, __hip_bfloat16* __restrict__ bot_out)
{
    if (blockIdx.x >= CVT_BLOCKS) {
        // bottom layer 0: fp32 VALU (K=13), bf16 out
        const int idx = (blockIdx.x - CVT_BLOCKS) * 256 + threadIdx.x;  // m*512 + n
        const int m = idx >> 9, n = idx & 511;
        float s = bb0[n];
        #pragma unroll
        for (int k = 0; k < 13; ++k) s += dense[m * 13 + k] * Wb0[k * 512 + n];
        s = s > 0.f ? s : 0.f;
        bot_out[idx] = __float2bfloat16(s);
        return;
    }
    int i = blockIdx.x * 256 + threadIdx.x;
    if (i < CVT0) { cvt_one(i, Wb1, Wb1t, 512, 256, 512); return; }
    i -= CVT0;
    if (i < CVT1) { cvt_one(i, Wb2, Wb2t, 256, 64, 256); return; }
    i -= CVT1;
    if (i < CVT2) { cvt_one(i, Wt0, Wt0t, 415, 512, 416); return; }
    i -= CVT2;
    if (i < CVT3) { cvt_one(i, Wt1, Wt1t, 512, 256, 512); return; }
    i -= CVT3;
    if (i < 128)  { bb2p[i] = (i < 64) ? bb2[i] : 0.f; }
}

// ---------------- gather + pairwise interaction -> h bf16 [B,416] ----------
// 1 sample per wave. Register-staged gather (26 loads in flight), Gram via
// 2x2 tiles of mfma_f32_16x16x32_bf16 over K=64 (A=B=T, Z symmetric),
// h-row assembled in LDS, stored as one coalesced 16B burst.
__global__ __launch_bounds__(256) void interact_kernel(
    const float* __restrict__ d,     // [B][128] (padded, cols 0..63 valid)
    const int* __restrict__ idx,     // [B][26]
    const float* __restrict__ emb,   // [26][VOCAB][64]
    __hip_bfloat16* __restrict__ h)  // [B][416]
{
    __shared__ __align__(16) __hip_bfloat16 T[4][32][68];   // pad 68: 136B rows, 2-way banks
    __shared__ __align__(16) __hip_bfloat16 Hrow[4][HPAD];
    const int wave = threadIdx.x >> 6;
    const int lane = threadIdx.x & 63;
    const int b = blockIdx.x * 4 + wave;

    // ---- gather: all 26 idx loads, then all 26 row gathers, all in flight ----
    int ix[NTAB];
    #pragma unroll
    for (int t = 0; t < NTAB; ++t) ix[t] = idx[b * NTAB + t];
    float rv[NTAB];
    #pragma unroll
    for (int t = 0; t < NTAB; ++t)
        rv[t] = emb[((size_t)t * VOCAB + (size_t)ix[t]) * MSPA + lane];
    const float dv = d[(size_t)b * 128 + lane];

    #pragma unroll
    for (int t = 0; t < NTAB; ++t) T[wave][t][lane] = __float2bfloat16(rv[t]);
    T[wave][NTAB][lane] = __float2bfloat16(dv);      // row 26 = d; rows 27..31 unused
    Hrow[wave][lane]    = __float2bfloat16(dv);      // h[0..63] = d
    if (lane == 0) Hrow[wave][HPAD - 1] = __float2bfloat16(0.f);
    __syncthreads();

    // ---- Gram Z = T T^T via MFMA: 2x2 16x16 tiles, K=64 in 2 steps ----
    const __hip_bfloat16* tr = &T[wave][lane & 15][(lane >> 4) * 8];
    bf16x8 fr[2][2];
    #pragma unroll
    for (int I = 0; I < 2; ++I)
        #pragma unroll
        for (int s = 0; s < 2; ++s) {
            const __hip_bfloat16* p0 = tr + I * 16 * 68 + s * 32;
            bf16x4 lo = *(const bf16x4*)(p0);
            bf16x4 hi = *(const bf16x4*)(p0 + 4);
            fr[I][s] = __builtin_shufflevector(lo, hi, 0, 1, 2, 3, 4, 5, 6, 7);
        }
    f32x4 az[2][2] = {};
    #pragma unroll
    for (int s = 0; s < 2; ++s)
        #pragma unroll
        for (int I = 0; I < 2; ++I)
            #pragma unroll
            for (int J = 0; J < 2; ++J)
                az[I][J] = __builtin_amdgcn_mfma_f32_16x16x32_bf16(fr[I][s], fr[J][s], az[I][J], 0, 0, 0);

    // ---- extract tril (i>j, i<27) into Hrow[64 + i*(i-1)/2 + j] ----
    #pragma unroll
    for (int I = 0; I < 2; ++I)
        #pragma unroll
        for (int J = 0; J < 2; ++J) {
            const int col = J * 16 + (lane & 15);
            const int rw0 = I * 16 + (lane >> 4) * 4;
            #pragma unroll
            for (int r = 0; r < 4; ++r) {
                const int row = rw0 + r;
                if (row < NTAB + 1 && col < row)
                    Hrow[wave][MSPA + (row * (row - 1)) / 2 + col] = __float2bfloat16(az[I][J][r]);
            }
        }
    __syncthreads();

    // ---- coalesced store: 416 bf16 = 832 B = 52 lanes x 16 B ----
    if (lane < 52)
        ((f32x4*)(h + (size_t)b * HPAD))[lane] = ((const f32x4*)&Hrow[wave][0])[lane];
}

// ---------------- final: dot(256) + bias + sigmoid ----------------
__global__ __launch_bounds__(256) void final_kernel(
    const __hip_bfloat16* __restrict__ X,  // [B][256] bf16
    const float* __restrict__ w,           // [256]
    const float* __restrict__ b2, float* __restrict__ out)
{
    const int wave = threadIdx.x >> 6;
    const int lane = threadIdx.x & 63;
    const int row = blockIdx.x * 4 + wave;
    const __hip_bfloat16* x = X + (size_t)row * 256;
    float s = 0.f;
    #pragma unroll
    for (int k = 0; k < 4; ++k)
        s += __bfloat162float(x[lane + 64 * k]) * w[lane + 64 * k];
    #pragma unroll
    for (int off = 32; off > 0; off >>= 1) s += __shfl_down(s, off, 64);
    if (lane == 0) out[row] = 1.f / (1.f + expf(-(s + b2[0])));
}

extern "C" void kernel_launch(void* const* d_in, const int* in_sizes, int n_in,
                              void* d_out, int out_size, void* d_ws, size_t ws_size,
                              hipStream_t stream)
{
    const float* dense = (const float*)d_in[0];
    const int*   sidx  = (const int*)d_in[1];
    const float* emb   = (const float*)d_in[2];
    const float* Wb0   = (const float*)d_in[3];
    const float* bb0   = (const float*)d_in[4];
    const float* Wb1   = (const float*)d_in[5];
    const float* bb1   = (const float*)d_in[6];
    const float* Wb2   = (const float*)d_in[7];
    const float* bb2   = (const float*)d_in[8];
    const float* Wt0   = (const float*)d_in[9];
    const float* bt0   = (const float*)d_in[10];
    const float* Wt1   = (const float*)d_in[11];
    const float* bt1   = (const float*)d_in[12];
    const float* Wt2   = (const float*)d_in[13];
    const float* bt2   = (const float*)d_in[14];

    char* p = (char*)d_ws;
    auto alloc = [&](size_t bytes) { char* r = p; p += (bytes + 255) & ~(size_t)255; return r; };
    __hip_bfloat16* Wb1t = (__hip_bfloat16*)alloc((size_t)CVT0 * 2);
    __hip_bfloat16* Wb2t = (__hip_bfloat16*)alloc((size_t)CVT1 * 2);
    __hip_bfloat16* Wt0t = (__hip_bfloat16*)alloc((size_t)CVT2 * 2);
    __hip_bfloat16* Wt1t = (__hip_bfloat16*)alloc((size_t)CVT3 * 2);
    float*          bb2p = (float*)alloc(128 * 4);
    __hip_bfloat16* x512 = (__hip_bfloat16*)alloc((size_t)BATCH * 512 * 2);
    __hip_bfloat16* x256 = (__hip_bfloat16*)alloc((size_t)BATCH * 256 * 2);
    float*          dbuf = (float*)alloc((size_t)BATCH * 128 * 4);
    __hip_bfloat16* hbuf = (__hip_bfloat16*)alloc((size_t)BATCH * HPAD * 2);

    // weight convert/transpose + bottom layer 0 (fused, disjoint block ranges)
    fused_cvt_bot0<<<CVT_BLOCKS + BATCH * 512 / 256, 256, 0, stream>>>(
        Wb1, Wb2, Wt0, Wt1, bb2, Wb1t, Wb2t, Wt0t, Wt1t, bb2p,
        dense, Wb0, bb0, x512);

    // bottom MLP
    mfma_gemm64<__hip_bfloat16><<<dim3(256 / 64, BATCH / 128), 256, 0, stream>>>(
        x512, Wb1t, bb1, x256, BATCH, 256, 512);
    mfma_gemm64<float><<<dim3(128 / 64, BATCH / 128), 256, 0, stream>>>(
        x256, Wb2t, bb2p, dbuf, BATCH, 128, 256);

    // gather + interaction
    interact_kernel<<<BATCH / 4, 256, 0, stream>>>(dbuf, sidx, emb, hbuf);

    // top MLP
    mfma_gemm64<__hip_bfloat16><<<dim3(512 / 64, BATCH / 128), 256, 0, stream>>>(
        hbuf, Wt0t, bt0, x512, BATCH, 512, HPAD);
    mfma_gemm64<__hip_bfloat16><<<dim3(256 / 64, BATCH / 128), 256, 0, stream>>>(
        x512, Wt1t, bt1, x256, BATCH, 256, 512);

    // final
    final_kernel<<<BATCH / 4, 256, 0, stream>>>(x256, Wt2, bt2, (float*)d_out);
}